// Round 2
// baseline (1107.659 us; speedup 1.0000x reference)
//
#include <hip/hip_runtime.h>

// RGCN: N=50000, E=1.6M, R=8, 128 -> 64 -> 64. Transform-then-gather:
//   xw[n][r*64+h] = (A @ W_rel[r])[n][h]  (node-major => 256B contiguous gather)
//   root+bias written by the same GEMM into the layer accumulator.
//   Edge pass: one wave/edge; lane h gathers xw[src][et*64+h], scales by
//   1/cnt(dst,et), atomicAdd into accum[dst][h].
// Defensive this round: ws_size-adaptive layout (full 117MB path vs 27MB
// per-relation path) + index bounds guards (dtype mismatch -> absmax fail,
// not a memory fault).

constexpr int NN  = 50000;
constexpr int NE  = 1600000;
constexpr int NR  = 8;
constexpr int FIN = 128;
constexpr int FH  = 64;

__global__ void count_kernel(const int* __restrict__ dst, const int* __restrict__ et,
                             float* __restrict__ cnt) {
  int i = blockIdx.x * blockDim.x + threadIdx.x;
  if (i < NE) {
    const unsigned d = (unsigned)dst[i];
    const unsigned r = (unsigned)et[i];
    if (d < NN && r < NR) atomicAdd(&cnt[d * NR + r], 1.0f);
  }
}

__global__ void inv_kernel(float* __restrict__ cnt) {
  int i = blockIdx.x * blockDim.x + threadIdx.x;
  if (i < NN * NR) cnt[i] = 1.0f / fmaxf(cnt[i], 1.0f);
}

// C = A[64-node tile, K] @ W for column group g = gbase + blockIdx.y
// (0..7 = relations, 8 = root). A tile transposed in LDS (As[k][n]):
// bank = n%32, conflict-free.
template <int K, bool RELU>
__global__ void __launch_bounds__(256) gemm_fused(
    const float* __restrict__ A, const float* __restrict__ Wrel,
    const float* __restrict__ Wroot, const float* __restrict__ bias,
    float* __restrict__ xw, int xw_stride, int gbase,
    float* __restrict__ root_out) {
  __shared__ float As[K * 64];
  __shared__ float Ws[K * 64];
  const int g  = gbase + blockIdx.y;
  const int n0 = blockIdx.x * 64;
  const float* __restrict__ W = (g < NR) ? (Wrel + (size_t)g * K * 64) : Wroot;
  const int tid = threadIdx.x;

  for (int f = tid; f < 16 * K; f += 256) {
    const int n  = f / (K / 4);
    const int kq = (f % (K / 4)) * 4;
    float4 v = make_float4(0.f, 0.f, 0.f, 0.f);
    if (n0 + n < NN) {
      v = *(const float4*)(A + (size_t)(n0 + n) * K + kq);
      if (RELU) {
        v.x = fmaxf(v.x, 0.f); v.y = fmaxf(v.y, 0.f);
        v.z = fmaxf(v.z, 0.f); v.w = fmaxf(v.w, 0.f);
      }
    }
    As[(kq + 0) * 64 + n] = v.x;
    As[(kq + 1) * 64 + n] = v.y;
    As[(kq + 2) * 64 + n] = v.z;
    As[(kq + 3) * 64 + n] = v.w;
  }
  for (int f = tid; f < 16 * K; f += 256) {
    ((float4*)Ws)[f] = ((const float4*)W)[f];
  }
  __syncthreads();

  const int tx = tid & 15;   // cols 4*tx..4*tx+3
  const int ty = tid >> 4;   // nodes 4*ty..4*ty+3
  float acc[4][4] = {};
#pragma unroll 8
  for (int k = 0; k < K; ++k) {
    const float4 a = *(const float4*)&As[k * 64 + ty * 4];
    const float4 w = *(const float4*)&Ws[k * 64 + tx * 4];
    const float av[4] = {a.x, a.y, a.z, a.w};
    const float wv[4] = {w.x, w.y, w.z, w.w};
#pragma unroll
    for (int i = 0; i < 4; ++i)
#pragma unroll
      for (int j = 0; j < 4; ++j) acc[i][j] += av[i] * wv[j];
  }

#pragma unroll
  for (int i = 0; i < 4; ++i) {
    const int n = n0 + ty * 4 + i;
    if (n >= NN) continue;
    float4 o = make_float4(acc[i][0], acc[i][1], acc[i][2], acc[i][3]);
    if (g < NR) {
      const int coff = (g - gbase) * 64;
      *(float4*)(xw + (size_t)n * xw_stride + coff + tx * 4) = o;
    } else {
      const float4 b = *(const float4*)(bias + tx * 4);
      o.x += b.x; o.y += b.y; o.z += b.z; o.w += b.w;
      *(float4*)(root_out + (size_t)n * 64 + tx * 4) = o;
    }
  }
}

// Full path: one wave per edge, xw holds all 8 relations (stride 512).
__global__ void __launch_bounds__(256) agg_kernel(
    const int* __restrict__ src, const int* __restrict__ dst,
    const int* __restrict__ et, const float* __restrict__ inv,
    const float* __restrict__ xw, float* __restrict__ out) {
  const int gid    = blockIdx.x * blockDim.x + threadIdx.x;
  const int lane   = gid & 63;
  const int wave   = gid >> 6;
  const int nwaves = (gridDim.x * blockDim.x) >> 6;
  for (int e = wave; e < NE; e += nwaves) {
    const unsigned s = (unsigned)src[e];
    const unsigned d = (unsigned)dst[e];
    const unsigned r = (unsigned)et[e];
    if (s >= NN || d >= NN || r >= NR) continue;
    const float sc = inv[d * NR + r];
    const float v  = xw[(size_t)s * (NR * 64) + r * 64 + lane] * sc;
    atomicAdd(out + (size_t)d * 64 + lane, v);
  }
}

// Per-relation path: xw_r has stride 64, only edges with et==rel contribute.
__global__ void __launch_bounds__(256) agg_rel_kernel(
    const int* __restrict__ src, const int* __restrict__ dst,
    const int* __restrict__ et, const float* __restrict__ inv,
    const float* __restrict__ xw, float* __restrict__ out, int rel) {
  const int gid    = blockIdx.x * blockDim.x + threadIdx.x;
  const int lane   = gid & 63;
  const int wave   = gid >> 6;
  const int nwaves = (gridDim.x * blockDim.x) >> 6;
  for (int e = wave; e < NE; e += nwaves) {
    if (et[e] != rel) continue;
    const unsigned s = (unsigned)src[e];
    const unsigned d = (unsigned)dst[e];
    if (s >= NN || d >= NN) continue;
    const float sc = inv[d * NR + rel];
    const float v  = xw[(size_t)s * 64 + lane] * sc;
    atomicAdd(out + (size_t)d * 64 + lane, v);
  }
}

extern "C" void kernel_launch(void* const* d_in, const int* in_sizes, int n_in,
                              void* d_out, int out_size, void* d_ws, size_t ws_size,
                              hipStream_t stream) {
  const float* x   = (const float*)d_in[0];
  const int*   ei  = (const int*)d_in[1];
  const int*   et  = (const int*)d_in[2];
  const float* W1r = (const float*)d_in[3];
  const float* W1o = (const float*)d_in[4];
  const float* b1  = (const float*)d_in[5];
  const float* W2r = (const float*)d_in[6];
  const float* W2o = (const float*)d_in[7];
  const float* b2  = (const float*)d_in[8];
  float* out = (float*)d_out;

  const int* src = ei;        // edge_index[0]
  const int* dst = ei + NE;   // edge_index[1]

  char* ws = (char*)d_ws;
  const size_t SZ_INV = (size_t)NN * NR * sizeof(float);        // 1.6 MB
  const size_t SZ_XW  = (size_t)NN * NR * 64 * sizeof(float);   // 102.4 MB
  const size_t SZ_XR  = (size_t)NN * 64 * sizeof(float);        // 12.8 MB
  const size_t SZ_H   = (size_t)NN * 64 * sizeof(float);        // 12.8 MB

  float* inv = (float*)ws;
  hipMemsetAsync(inv, 0, SZ_INV, stream);
  count_kernel<<<(NE + 255) / 256, 256, 0, stream>>>(dst, et, inv);
  inv_kernel<<<(NN * NR + 255) / 256, 256, 0, stream>>>(inv);

  const int NBX = (NN + 63) / 64;

  if (ws_size >= SZ_INV + SZ_XW + SZ_H) {
    // ---- full path: all relations materialized at once ----
    float* xw = (float*)(ws + SZ_INV);
    float* h  = (float*)(ws + SZ_INV + SZ_XW);
    dim3 gg(NBX, NR + 1);
    gemm_fused<FIN, false><<<gg, 256, 0, stream>>>(x, W1r, W1o, b1, xw, NR * 64, 0, h);
    agg_kernel<<<2048, 256, 0, stream>>>(src, dst, et, inv, xw, h);
    gemm_fused<FH, true><<<gg, 256, 0, stream>>>(h, W2r, W2o, b2, xw, NR * 64, 0, out);
    agg_kernel<<<2048, 256, 0, stream>>>(src, dst, et, inv, xw, out);
  } else {
    // ---- compact path: one relation at a time (needs ~27.2 MB) ----
    float* xwr = (float*)(ws + SZ_INV);
    float* h   = (float*)(ws + SZ_INV + SZ_XR);
    dim3 g1(NBX, 1);
    // layer 1: root first (initializes h), then relations
    gemm_fused<FIN, false><<<g1, 256, 0, stream>>>(x, W1r, W1o, b1, xwr, 64, NR, h);
    for (int r = 0; r < NR; ++r) {
      gemm_fused<FIN, false><<<g1, 256, 0, stream>>>(x, W1r, W1o, b1, xwr, 64, r, h);
      agg_rel_kernel<<<2048, 256, 0, stream>>>(src, dst, et, inv, xwr, h, r);
    }
    // layer 2
    gemm_fused<FH, true><<<g1, 256, 0, stream>>>(h, W2r, W2o, b2, xwr, 64, NR, out);
    for (int r = 0; r < NR; ++r) {
      gemm_fused<FH, true><<<g1, 256, 0, stream>>>(h, W2r, W2o, b2, xwr, 64, r, out);
      agg_rel_kernel<<<2048, 256, 0, stream>>>(src, dst, et, inv, xwr, out, r);
    }
  }
}

// Round 3
// 647.946 us; speedup vs baseline: 1.7095x; 1.7095x over previous
//
#include <hip/hip_runtime.h>

// RGCN: N=50000, E=1.6M, R=8, 128 -> 64 -> 64.
// R3: transform-then-gather with CSR aggregation (no fp32 atomics in hot loop).
//   1. int histogram cnt[(dst,rel)]; inv scale; wave-scan -> row_start per dst.
//   2. scatter: recs[pos] = {src*512 + rel*64, scale}  (dst-grouped).
//   3. gemm: xw[n][r*64+h] in BF16 (halves gather bytes); root+bias fp32 -> acc.
//   4. agg: one wave per dst node; register accumulate; single += store.

constexpr int NN  = 50000;
constexpr int NE  = 1600000;
constexpr int NR  = 8;
constexpr int FIN = 128;
constexpr int FH  = 64;

__device__ __forceinline__ unsigned short f2bf(float f) {
  unsigned u = __float_as_uint(f);
  u = (u + 0x7fff + ((u >> 16) & 1)) >> 16;   // round-to-nearest-even
  return (unsigned short)u;
}
__device__ __forceinline__ float bf2f(unsigned short b) {
  return __uint_as_float(((unsigned)b) << 16);
}

__global__ void count_kernel(const int* __restrict__ dst, const int* __restrict__ et,
                             int* __restrict__ cnt) {
  int i = blockIdx.x * blockDim.x + threadIdx.x;
  if (i < NE) {
    const unsigned d = (unsigned)dst[i];
    const unsigned r = (unsigned)et[i];
    if (d < NN && r < NR) atomicAdd(&cnt[(d << 3) | r], 1);
  }
}

// One lane per node: inv scales, degree, wave-scan -> row_start, cur.
__global__ void __launch_bounds__(256) node_setup(
    const int* __restrict__ cnt, float* __restrict__ inv,
    int* __restrict__ row_start, int* __restrict__ deg_out,
    int* __restrict__ cur, int* __restrict__ cursor) {
  const int gid  = blockIdx.x * blockDim.x + threadIdx.x;
  const int lane = gid & 63;
  const int d    = gid;
  int deg = 0;
  if (d < NN) {
    const int4 c0 = *(const int4*)(cnt + (d << 3));
    const int4 c1 = *(const int4*)(cnt + (d << 3) + 4);
    deg = c0.x + c0.y + c0.z + c0.w + c1.x + c1.y + c1.z + c1.w;
    float iv[8] = {
      1.0f / fmaxf((float)c0.x, 1.0f), 1.0f / fmaxf((float)c0.y, 1.0f),
      1.0f / fmaxf((float)c0.z, 1.0f), 1.0f / fmaxf((float)c0.w, 1.0f),
      1.0f / fmaxf((float)c1.x, 1.0f), 1.0f / fmaxf((float)c1.y, 1.0f),
      1.0f / fmaxf((float)c1.z, 1.0f), 1.0f / fmaxf((float)c1.w, 1.0f)};
    *(float4*)(inv + (d << 3))     = make_float4(iv[0], iv[1], iv[2], iv[3]);
    *(float4*)(inv + (d << 3) + 4) = make_float4(iv[4], iv[5], iv[6], iv[7]);
  }
  // inclusive wave scan of deg
  int incl = deg;
#pragma unroll
  for (int off = 1; off < 64; off <<= 1) {
    int t = __shfl_up(incl, off, 64);
    if (lane >= off) incl += t;
  }
  int total = __shfl(incl, 63, 64);
  int waveBase = 0;
  if (lane == 63) waveBase = atomicAdd(cursor, total);
  waveBase = __shfl(waveBase, 63, 64);
  if (d < NN) {
    const int rs = waveBase + incl - deg;
    row_start[d] = rs;
    deg_out[d]   = deg;
    cur[d]       = rs;
  }
}

__global__ void scatter_kernel(const int* __restrict__ src, const int* __restrict__ dst,
                               const int* __restrict__ et, const float* __restrict__ inv,
                               int* __restrict__ cur, uint2* __restrict__ recs) {
  int i = blockIdx.x * blockDim.x + threadIdx.x;
  if (i < NE) {
    const unsigned s = (unsigned)src[i];
    const unsigned d = (unsigned)dst[i];
    const unsigned r = (unsigned)et[i];
    if (s < NN && d < NN && r < NR) {
      const int pos = atomicAdd(&cur[d], 1);
      recs[pos] = make_uint2(s * (NR * 64) + r * 64,
                             __float_as_uint(inv[(d << 3) | r]));
    }
  }
}

// C = A[64-node tile, K] @ W for group g = blockIdx.y (0..7 rel -> bf16 xw,
// 8 = root -> fp32 out + bias).
template <int K, bool RELU>
__global__ void __launch_bounds__(256) gemm_fused(
    const float* __restrict__ A, const float* __restrict__ Wrel,
    const float* __restrict__ Wroot, const float* __restrict__ bias,
    unsigned short* __restrict__ xw, float* __restrict__ root_out) {
  __shared__ float As[K * 64];
  __shared__ float Ws[K * 64];
  const int g  = blockIdx.y;
  const int n0 = blockIdx.x * 64;
  const float* __restrict__ W = (g < NR) ? (Wrel + (size_t)g * K * 64) : Wroot;
  const int tid = threadIdx.x;

  for (int f = tid; f < 16 * K; f += 256) {
    const int n  = f / (K / 4);
    const int kq = (f % (K / 4)) * 4;
    float4 v = make_float4(0.f, 0.f, 0.f, 0.f);
    if (n0 + n < NN) {
      v = *(const float4*)(A + (size_t)(n0 + n) * K + kq);
      if (RELU) {
        v.x = fmaxf(v.x, 0.f); v.y = fmaxf(v.y, 0.f);
        v.z = fmaxf(v.z, 0.f); v.w = fmaxf(v.w, 0.f);
      }
    }
    As[(kq + 0) * 64 + n] = v.x;
    As[(kq + 1) * 64 + n] = v.y;
    As[(kq + 2) * 64 + n] = v.z;
    As[(kq + 3) * 64 + n] = v.w;
  }
  for (int f = tid; f < 16 * K; f += 256) {
    ((float4*)Ws)[f] = ((const float4*)W)[f];
  }
  __syncthreads();

  const int tx = tid & 15;
  const int ty = tid >> 4;
  float acc[4][4] = {};
#pragma unroll 8
  for (int k = 0; k < K; ++k) {
    const float4 a = *(const float4*)&As[k * 64 + ty * 4];
    const float4 w = *(const float4*)&Ws[k * 64 + tx * 4];
    const float av[4] = {a.x, a.y, a.z, a.w};
    const float wv[4] = {w.x, w.y, w.z, w.w};
#pragma unroll
    for (int i = 0; i < 4; ++i)
#pragma unroll
      for (int j = 0; j < 4; ++j) acc[i][j] += av[i] * wv[j];
  }

#pragma unroll
  for (int i = 0; i < 4; ++i) {
    const int n = n0 + ty * 4 + i;
    if (n >= NN) continue;
    if (g < NR) {
      ushort4 o;
      o.x = f2bf(acc[i][0]); o.y = f2bf(acc[i][1]);
      o.z = f2bf(acc[i][2]); o.w = f2bf(acc[i][3]);
      *(ushort4*)(xw + (size_t)n * (NR * 64) + g * 64 + tx * 4) = o;
    } else {
      const float4 b = *(const float4*)(bias + tx * 4);
      float4 o = make_float4(acc[i][0] + b.x, acc[i][1] + b.y,
                             acc[i][2] + b.z, acc[i][3] + b.w);
      *(float4*)(root_out + (size_t)n * 64 + tx * 4) = o;
    }
  }
}

// One wave per dst node: register accumulation, no atomics.
__global__ void __launch_bounds__(256) agg_csr(
    const int* __restrict__ row_start, const int* __restrict__ deg,
    const uint2* __restrict__ recs, const unsigned short* __restrict__ xw,
    float* __restrict__ out) {
  const int gid  = blockIdx.x * blockDim.x + threadIdx.x;
  const int lane = gid & 63;
  const int d    = gid >> 6;
  if (d >= NN) return;
  const int base = row_start[d];
  const int n    = deg[d];
  float acc0 = 0.f, acc1 = 0.f;
  int j = 0;
  for (; j + 2 <= n; j += 2) {
    const uint2 r0 = recs[base + j];
    const uint2 r1 = recs[base + j + 1];
    const float v0 = bf2f(xw[r0.x + lane]);
    const float v1 = bf2f(xw[r1.x + lane]);
    acc0 += v0 * __uint_as_float(r0.y);
    acc1 += v1 * __uint_as_float(r1.y);
  }
  if (j < n) {
    const uint2 r0 = recs[base + j];
    acc0 += bf2f(xw[r0.x + lane]) * __uint_as_float(r0.y);
  }
  out[(size_t)d * 64 + lane] += acc0 + acc1;
}

extern "C" void kernel_launch(void* const* d_in, const int* in_sizes, int n_in,
                              void* d_out, int out_size, void* d_ws, size_t ws_size,
                              hipStream_t stream) {
  const float* x   = (const float*)d_in[0];
  const int*   ei  = (const int*)d_in[1];
  const int*   et  = (const int*)d_in[2];
  const float* W1r = (const float*)d_in[3];
  const float* W1o = (const float*)d_in[4];
  const float* b1  = (const float*)d_in[5];
  const float* W2r = (const float*)d_in[6];
  const float* W2o = (const float*)d_in[7];
  const float* b2  = (const float*)d_in[8];
  float* out = (float*)d_out;

  const int* src = ei;
  const int* dst = ei + NE;

  char* ws = (char*)d_ws;
  size_t off = 0;
  auto alloc = [&](size_t bytes) { void* p = ws + off; off += (bytes + 255) & ~(size_t)255; return p; };
  int*   cnt       = (int*)alloc((size_t)NN * NR * 4);      // 1.6 MB
  float* inv       = (float*)alloc((size_t)NN * NR * 4);    // 1.6 MB
  int*   row_start = (int*)alloc((size_t)NN * 4);
  int*   deg       = (int*)alloc((size_t)NN * 4);
  int*   cur       = (int*)alloc((size_t)NN * 4);
  int*   cursor    = (int*)alloc(256);
  uint2* recs      = (uint2*)alloc((size_t)NE * 8);         // 12.8 MB
  unsigned short* xw = (unsigned short*)alloc((size_t)NN * NR * 64 * 2); // 51.2 MB
  float* h         = (float*)alloc((size_t)NN * 64 * 4);    // 12.8 MB

  hipMemsetAsync(cnt, 0, (size_t)NN * NR * 4, stream);
  hipMemsetAsync(cursor, 0, 256, stream);

  count_kernel<<<(NE + 255) / 256, 256, 0, stream>>>(dst, et, cnt);
  node_setup<<<(NN + 255) / 256, 256, 0, stream>>>(cnt, inv, row_start, deg, cur, cursor);
  scatter_kernel<<<(NE + 255) / 256, 256, 0, stream>>>(src, dst, et, inv, cur, recs);

  dim3 gg((NN + 63) / 64, NR + 1);
  const int agg_blocks = (NN * 64 + 255) / 256;
  // Layer 1
  gemm_fused<FIN, false><<<gg, 256, 0, stream>>>(x, W1r, W1o, b1, xw, h);
  agg_csr<<<agg_blocks, 256, 0, stream>>>(row_start, deg, recs, xw, h);
  // Layer 2 (ReLU fused into A load)
  gemm_fused<FH, true><<<gg, 256, 0, stream>>>(h, W2r, W2o, b2, xw, out);
  agg_csr<<<agg_blocks, 256, 0, stream>>>(row_start, deg, recs, xw, out);
}

// Round 4
// 479.300 us; speedup vs baseline: 2.3110x; 1.3519x over previous
//
#include <hip/hip_runtime.h>

// RGCN: N=50000, E=1.6M, R=8, 128 -> 64 -> 64.
// R4: bf16 MFMA GEMMs (16x16x32), CSR aggregation (no atomics), bf16 xw gather.
//   prep:  cnt[(dst,rel)] -> inv, CSR row_start/deg, recs {gather_off, scale}
//   cvt:   x -> bf16; weights -> bf16 TRANSPOSED Wt[g][n][k] (frag-contiguous)
//   gemm:  128-node x 64-col tile per block, K resident, 4 waves x 8 MFMA tiles
//          groups 0..7 -> xw bf16 [n][r*64+h]; group 8 -> root fp32 + bias
//   agg:   one wave per dst; register accumulate; layer1 fuses relu->bf16.

constexpr int NN  = 50000;
constexpr int NE  = 1600000;
constexpr int NR  = 8;
constexpr int FIN = 128;
constexpr int FH  = 64;

typedef __attribute__((ext_vector_type(8))) short bf16x8;   // 8 bf16 (4 VGPRs)
typedef __attribute__((ext_vector_type(4))) float f32x4;

__device__ __forceinline__ unsigned short f2bf(float f) {
  unsigned u = __float_as_uint(f);
  u = (u + 0x7fff + ((u >> 16) & 1)) >> 16;   // RNE
  return (unsigned short)u;
}
__device__ __forceinline__ float bf2f(unsigned short b) {
  return __uint_as_float(((unsigned)b) << 16);
}

// ---------------- prep ----------------
__global__ void count_kernel(const int* __restrict__ dst, const int* __restrict__ et,
                             int* __restrict__ cnt) {
  int i = blockIdx.x * blockDim.x + threadIdx.x;
  if (i < NE) {
    const unsigned d = (unsigned)dst[i];
    const unsigned r = (unsigned)et[i];
    if (d < NN && r < NR) atomicAdd(&cnt[(d << 3) | r], 1);
  }
}

__global__ void __launch_bounds__(256) node_setup(
    const int* __restrict__ cnt, float* __restrict__ inv,
    int* __restrict__ row_start, int* __restrict__ deg_out,
    int* __restrict__ cur, int* __restrict__ cursor) {
  const int gid  = blockIdx.x * blockDim.x + threadIdx.x;
  const int lane = gid & 63;
  const int d    = gid;
  int deg = 0;
  if (d < NN) {
    const int4 c0 = *(const int4*)(cnt + (d << 3));
    const int4 c1 = *(const int4*)(cnt + (d << 3) + 4);
    deg = c0.x + c0.y + c0.z + c0.w + c1.x + c1.y + c1.z + c1.w;
    *(float4*)(inv + (d << 3)) = make_float4(
        1.0f / fmaxf((float)c0.x, 1.0f), 1.0f / fmaxf((float)c0.y, 1.0f),
        1.0f / fmaxf((float)c0.z, 1.0f), 1.0f / fmaxf((float)c0.w, 1.0f));
    *(float4*)(inv + (d << 3) + 4) = make_float4(
        1.0f / fmaxf((float)c1.x, 1.0f), 1.0f / fmaxf((float)c1.y, 1.0f),
        1.0f / fmaxf((float)c1.z, 1.0f), 1.0f / fmaxf((float)c1.w, 1.0f));
  }
  int incl = deg;
#pragma unroll
  for (int off = 1; off < 64; off <<= 1) {
    int t = __shfl_up(incl, off, 64);
    if (lane >= off) incl += t;
  }
  int total = __shfl(incl, 63, 64);
  int waveBase = 0;
  if (lane == 63) waveBase = atomicAdd(cursor, total);
  waveBase = __shfl(waveBase, 63, 64);
  if (d < NN) {
    const int rs = waveBase + incl - deg;
    row_start[d] = rs;
    deg_out[d]   = deg;
    cur[d]       = rs;
  }
}

__global__ void scatter_kernel(const int* __restrict__ src, const int* __restrict__ dst,
                               const int* __restrict__ et, const float* __restrict__ inv,
                               int* __restrict__ cur, uint2* __restrict__ recs) {
  int i = blockIdx.x * blockDim.x + threadIdx.x;
  if (i < NE) {
    const unsigned s = (unsigned)src[i];
    const unsigned d = (unsigned)dst[i];
    const unsigned r = (unsigned)et[i];
    if (s < NN && d < NN && r < NR) {
      const int pos = atomicAdd(&cur[d], 1);
      recs[pos] = make_uint2(s * (NR * 64) + r * 64,
                             __float_as_uint(inv[(d << 3) | r]));
    }
  }
}

// ---------------- converts ----------------
__global__ void cvt_x(const float* __restrict__ x, unsigned short* __restrict__ xb) {
  int i = blockIdx.x * blockDim.x + threadIdx.x;
  if (i < NN * FIN / 4) {
    float4 v = ((const float4*)x)[i];
    ushort4 o;
    o.x = f2bf(v.x); o.y = f2bf(v.y); o.z = f2bf(v.z); o.w = f2bf(v.w);
    ((ushort4*)xb)[i] = o;
  }
}

// W[g][k][n] fp32 -> Wt[g][n][k] bf16 (g<NR from Wrel, g==NR from Wroot)
template <int K>
__global__ void cvt_w(const float* __restrict__ Wrel, const float* __restrict__ Wroot,
                      unsigned short* __restrict__ Wt) {
  int i = blockIdx.x * blockDim.x + threadIdx.x;
  if (i >= (NR + 1) * 64 * K) return;
  const int g   = i / (64 * K);
  const int rem = i % (64 * K);
  const int n   = rem / K;
  const int k   = rem % K;
  const float* W = (g < NR) ? (Wrel + (size_t)g * K * 64) : Wroot;
  Wt[i] = f2bf(W[k * 64 + n]);
}

// ---------------- MFMA GEMM ----------------
// C[128 x 64] tile = A[128 x K] @ Wt[g][64 x K]^T for g = blockIdx.y.
// A,B frags both read as contiguous 16B from k-contiguous padded LDS rows.
template <int K>
__global__ void __launch_bounds__(256) gemm_mfma(
    const unsigned short* __restrict__ A,   // [NN][K] bf16
    const unsigned short* __restrict__ Wt,  // [(NR+1)][64][K] bf16
    const float* __restrict__ bias,
    unsigned short* __restrict__ xw,        // [NN][NR*64] bf16
    float* __restrict__ root_out) {         // [NN][64] fp32
  constexpr int KP = K + 8;                 // +16B pad: frag reads 2-way only
  __shared__ unsigned short As[128 * KP];
  __shared__ unsigned short Bs[64 * KP];
  const int g   = blockIdx.y;
  const int n0  = blockIdx.x * 128;
  const int tid = threadIdx.x;

  for (int c = tid; c < 128 * K / 8; c += 256) {
    const int row = c / (K / 8), kp = (c % (K / 8)) * 8;
    bf16x8 v = {};
    if (n0 + row < NN) v = *(const bf16x8*)(A + (size_t)(n0 + row) * K + kp);
    *(bf16x8*)(As + row * KP + kp) = v;
  }
  const unsigned short* Wg = Wt + (size_t)g * 64 * K;
  for (int c = tid; c < 64 * K / 8; c += 256) {
    const int row = c / (K / 8), kp = (c % (K / 8)) * 8;
    *(bf16x8*)(Bs + row * KP + kp) = *(const bf16x8*)(Wg + row * K + kp);
  }
  __syncthreads();

  const int wave = tid >> 6, lane = tid & 63;
  const int i16 = lane & 15, quad = lane >> 4;
  f32x4 acc[2][4] = {};
  const int r0 = wave * 32 + i16;
#pragma unroll
  for (int kc = 0; kc < K / 32; ++kc) {
    const int k0 = kc * 32 + quad * 8;
    const bf16x8 a0 = *(const bf16x8*)(As + (r0)      * KP + k0);
    const bf16x8 a1 = *(const bf16x8*)(As + (r0 + 16) * KP + k0);
    const bf16x8 b0 = *(const bf16x8*)(Bs + (i16)      * KP + k0);
    const bf16x8 b1 = *(const bf16x8*)(Bs + (i16 + 16) * KP + k0);
    const bf16x8 b2 = *(const bf16x8*)(Bs + (i16 + 32) * KP + k0);
    const bf16x8 b3 = *(const bf16x8*)(Bs + (i16 + 48) * KP + k0);
    acc[0][0] = __builtin_amdgcn_mfma_f32_16x16x32_bf16(a0, b0, acc[0][0], 0, 0, 0);
    acc[0][1] = __builtin_amdgcn_mfma_f32_16x16x32_bf16(a0, b1, acc[0][1], 0, 0, 0);
    acc[0][2] = __builtin_amdgcn_mfma_f32_16x16x32_bf16(a0, b2, acc[0][2], 0, 0, 0);
    acc[0][3] = __builtin_amdgcn_mfma_f32_16x16x32_bf16(a0, b3, acc[0][3], 0, 0, 0);
    acc[1][0] = __builtin_amdgcn_mfma_f32_16x16x32_bf16(a1, b0, acc[1][0], 0, 0, 0);
    acc[1][1] = __builtin_amdgcn_mfma_f32_16x16x32_bf16(a1, b1, acc[1][1], 0, 0, 0);
    acc[1][2] = __builtin_amdgcn_mfma_f32_16x16x32_bf16(a1, b2, acc[1][2], 0, 0, 0);
    acc[1][3] = __builtin_amdgcn_mfma_f32_16x16x32_bf16(a1, b3, acc[1][3], 0, 0, 0);
  }

  // C/D: row = quad*4 + reg (+tile), col = ct*16 + i16
  if (g < NR) {
#pragma unroll
    for (int rt = 0; rt < 2; ++rt)
#pragma unroll
      for (int reg = 0; reg < 4; ++reg) {
        const int n = n0 + wave * 32 + rt * 16 + quad * 4 + reg;
        if (n >= NN) continue;
        unsigned short* p = xw + (size_t)n * (NR * 64) + g * 64 + i16;
#pragma unroll
        for (int ct = 0; ct < 4; ++ct) p[ct * 16] = f2bf(acc[rt][ct][reg]);
      }
  } else {
    float bv[4];
#pragma unroll
    for (int ct = 0; ct < 4; ++ct) bv[ct] = bias[ct * 16 + i16];
#pragma unroll
    for (int rt = 0; rt < 2; ++rt)
#pragma unroll
      for (int reg = 0; reg < 4; ++reg) {
        const int n = n0 + wave * 32 + rt * 16 + quad * 4 + reg;
        if (n >= NN) continue;
        float* p = root_out + (size_t)n * 64 + i16;
#pragma unroll
        for (int ct = 0; ct < 4; ++ct) p[ct * 16] = acc[rt][ct][reg] + bv[ct];
      }
  }
}

// ---------------- aggregation ----------------
// One wave per dst node; layer1 fuses relu + bf16 convert for next GEMM.
template <bool RELU_BF16>
__global__ void __launch_bounds__(256) agg_csr(
    const int* __restrict__ row_start, const int* __restrict__ deg,
    const uint2* __restrict__ recs, const unsigned short* __restrict__ xw,
    const float* __restrict__ root, float* __restrict__ out_f32,
    unsigned short* __restrict__ out_b16) {
  const int gid  = blockIdx.x * blockDim.x + threadIdx.x;
  const int lane = gid & 63;
  const int d    = gid >> 6;
  if (d >= NN) return;
  const int base = row_start[d];
  const int n    = deg[d];
  float acc0 = 0.f, acc1 = 0.f;
  int j = 0;
  for (; j + 2 <= n; j += 2) {
    const uint2 e0 = recs[base + j];
    const uint2 e1 = recs[base + j + 1];
    acc0 += bf2f(xw[e0.x + lane]) * __uint_as_float(e0.y);
    acc1 += bf2f(xw[e1.x + lane]) * __uint_as_float(e1.y);
  }
  if (j < n) {
    const uint2 e0 = recs[base + j];
    acc0 += bf2f(xw[e0.x + lane]) * __uint_as_float(e0.y);
  }
  const float v = root[(size_t)d * 64 + lane] + acc0 + acc1;
  if (RELU_BF16) out_b16[(size_t)d * 64 + lane] = f2bf(fmaxf(v, 0.f));
  else           out_f32[(size_t)d * 64 + lane] = v;
}

extern "C" void kernel_launch(void* const* d_in, const int* in_sizes, int n_in,
                              void* d_out, int out_size, void* d_ws, size_t ws_size,
                              hipStream_t stream) {
  const float* x   = (const float*)d_in[0];
  const int*   ei  = (const int*)d_in[1];
  const int*   et  = (const int*)d_in[2];
  const float* W1r = (const float*)d_in[3];
  const float* W1o = (const float*)d_in[4];
  const float* b1  = (const float*)d_in[5];
  const float* W2r = (const float*)d_in[6];
  const float* W2o = (const float*)d_in[7];
  const float* b2  = (const float*)d_in[8];
  float* out = (float*)d_out;

  const int* src = ei;
  const int* dst = ei + NE;

  char* ws = (char*)d_ws;
  size_t off = 0;
  auto alloc = [&](size_t bytes) {
    void* p = ws + off; off += (bytes + 255) & ~(size_t)255; return p;
  };
  int*   cnt       = (int*)alloc((size_t)NN * NR * 4);
  float* inv       = (float*)alloc((size_t)NN * NR * 4);
  int*   row_start = (int*)alloc((size_t)NN * 4);
  int*   deg       = (int*)alloc((size_t)NN * 4);
  int*   cur       = (int*)alloc((size_t)NN * 4);
  int*   cursor    = (int*)alloc(256);
  uint2* recs      = (uint2*)alloc((size_t)NE * 8);                       // 12.8 MB
  unsigned short* xw   = (unsigned short*)alloc((size_t)NN * NR * 64 * 2); // 51.2 MB
  unsigned short* xb   = (unsigned short*)alloc((size_t)NN * FIN * 2);     // 12.8 MB
  unsigned short* hb   = (unsigned short*)alloc((size_t)NN * FH * 2);      //  6.4 MB
  float*          hroot= (float*)alloc((size_t)NN * 64 * 4);               // 12.8 MB
  unsigned short* Wt1  = (unsigned short*)alloc((size_t)(NR + 1) * 64 * FIN * 2);
  unsigned short* Wt2  = (unsigned short*)alloc((size_t)(NR + 1) * 64 * FH * 2);

  hipMemsetAsync(cnt, 0, (size_t)NN * NR * 4, stream);
  hipMemsetAsync(cursor, 0, 256, stream);

  count_kernel<<<(NE + 255) / 256, 256, 0, stream>>>(dst, et, cnt);
  node_setup<<<(NN + 255) / 256, 256, 0, stream>>>(cnt, inv, row_start, deg, cur, cursor);
  scatter_kernel<<<(NE + 255) / 256, 256, 0, stream>>>(src, dst, et, inv, cur, recs);

  cvt_x<<<(NN * FIN / 4 + 255) / 256, 256, 0, stream>>>(x, xb);
  cvt_w<FIN><<<((NR + 1) * 64 * FIN + 255) / 256, 256, 0, stream>>>(W1r, W1o, Wt1);
  cvt_w<FH><<<((NR + 1) * 64 * FH + 255) / 256, 256, 0, stream>>>(W2r, W2o, Wt2);

  dim3 gg((NN + 127) / 128, NR + 1);
  const int agg_blocks = (NN * 64 + 255) / 256;
  // Layer 1
  gemm_mfma<FIN><<<gg, 256, 0, stream>>>(xb, Wt1, b1, xw, hroot);
  agg_csr<true><<<agg_blocks, 256, 0, stream>>>(row_start, deg, recs, xw, hroot, nullptr, hb);
  // Layer 2
  gemm_mfma<FH><<<gg, 256, 0, stream>>>(hb, Wt2, b2, xw, out);
  agg_csr<false><<<agg_blocks, 256, 0, stream>>>(row_start, deg, recs, xw, out, out, nullptr);
}

// Round 5
// 410.654 us; speedup vs baseline: 2.6973x; 1.1672x over previous
//
#include <hip/hip_runtime.h>

// RGCN: N=50000, E=1.6M, R=8, 128 -> 64 -> 64.
// R5: 4B CSR records (scale recovered in agg via shfl of register inv),
//     agg with coalesced rec prefetch + shfl broadcast + unroll-4 gathers,
//     single-pass GEMM (A staged once, 9 weight groups looped in-block,
//     fp32->bf16 conversion of x fused into layer-1 A staging).

constexpr int NN  = 50000;
constexpr int NE  = 1600000;
constexpr int NR  = 8;
constexpr int FIN = 128;
constexpr int FH  = 64;

typedef __attribute__((ext_vector_type(8))) short bf16x8;   // 8 bf16 (4 VGPRs)
typedef __attribute__((ext_vector_type(4))) float f32x4;

__device__ __forceinline__ unsigned short f2bf(float f) {
  unsigned u = __float_as_uint(f);
  u = (u + 0x7fff + ((u >> 16) & 1)) >> 16;   // RNE
  return (unsigned short)u;
}
__device__ __forceinline__ float bf2f(unsigned short b) {
  return __uint_as_float(((unsigned)b) << 16);
}

// ---------------- prep ----------------
__global__ void count_kernel(const int* __restrict__ dst, const int* __restrict__ et,
                             int* __restrict__ cnt) {
  int i = blockIdx.x * blockDim.x + threadIdx.x;
  if (i < NE) {
    const unsigned d = (unsigned)dst[i];
    const unsigned r = (unsigned)et[i];
    if (d < NN && r < NR) atomicAdd(&cnt[(d << 3) | r], 1);
  }
}

__global__ void __launch_bounds__(256) node_setup(
    const int* __restrict__ cnt, float* __restrict__ inv,
    int* __restrict__ row_start, int* __restrict__ deg_out,
    int* __restrict__ cur, int* __restrict__ cursor) {
  const int gid  = blockIdx.x * blockDim.x + threadIdx.x;
  const int lane = gid & 63;
  const int d    = gid;
  int deg = 0;
  if (d < NN) {
    const int4 c0 = *(const int4*)(cnt + (d << 3));
    const int4 c1 = *(const int4*)(cnt + (d << 3) + 4);
    deg = c0.x + c0.y + c0.z + c0.w + c1.x + c1.y + c1.z + c1.w;
    *(float4*)(inv + (d << 3)) = make_float4(
        1.0f / fmaxf((float)c0.x, 1.0f), 1.0f / fmaxf((float)c0.y, 1.0f),
        1.0f / fmaxf((float)c0.z, 1.0f), 1.0f / fmaxf((float)c0.w, 1.0f));
    *(float4*)(inv + (d << 3) + 4) = make_float4(
        1.0f / fmaxf((float)c1.x, 1.0f), 1.0f / fmaxf((float)c1.y, 1.0f),
        1.0f / fmaxf((float)c1.z, 1.0f), 1.0f / fmaxf((float)c1.w, 1.0f));
  }
  int incl = deg;
#pragma unroll
  for (int off = 1; off < 64; off <<= 1) {
    int t = __shfl_up(incl, off, 64);
    if (lane >= off) incl += t;
  }
  int total = __shfl(incl, 63, 64);
  int waveBase = 0;
  if (lane == 63) waveBase = atomicAdd(cursor, total);
  waveBase = __shfl(waveBase, 63, 64);
  if (d < NN) {
    const int rs = waveBase + incl - deg;
    row_start[d] = rs;
    deg_out[d]   = deg;
    cur[d]       = rs;
  }
}

// 4-byte records: off = src*512 + rel*64 (rel = (off>>6)&7).
__global__ void scatter_kernel(const int* __restrict__ src, const int* __restrict__ dst,
                               const int* __restrict__ et,
                               int* __restrict__ cur, unsigned* __restrict__ offs) {
  int i = blockIdx.x * blockDim.x + threadIdx.x;
  if (i < NE) {
    const unsigned s = (unsigned)src[i];
    const unsigned d = (unsigned)dst[i];
    const unsigned r = (unsigned)et[i];
    if (s < NN && d < NN && r < NR) {
      const int pos = atomicAdd(&cur[d], 1);
      offs[pos] = (s << 9) | (r << 6);
    }
  }
}

// W[g][k][n] fp32 -> Wt[g][n][k] bf16 (g<NR from Wrel, g==NR from Wroot)
template <int K>
__global__ void cvt_w(const float* __restrict__ Wrel, const float* __restrict__ Wroot,
                      unsigned short* __restrict__ Wt) {
  int i = blockIdx.x * blockDim.x + threadIdx.x;
  if (i >= (NR + 1) * 64 * K) return;
  const int g   = i / (64 * K);
  const int rem = i % (64 * K);
  const int n   = rem / K;
  const int k   = rem % K;
  const float* W = (g < NR) ? (Wrel + (size_t)g * K * 64) : Wroot;
  Wt[i] = f2bf(W[k * 64 + n]);
}

// ---------------- MFMA GEMM ----------------
// Block = 64 nodes. A staged once (fp32->bf16 fused if A_FP32); loop over
// 9 weight groups (0..7 rel -> bf16 xw, 8 root -> fp32 + bias).
template <int K, bool A_FP32>
__global__ void __launch_bounds__(256) gemm_mfma(
    const void* __restrict__ Av, const unsigned short* __restrict__ Wt,
    const float* __restrict__ bias,
    unsigned short* __restrict__ xw, float* __restrict__ root_out) {
  constexpr int KP = K + 8;
  __shared__ unsigned short As[64 * KP];
  __shared__ unsigned short Bs[64 * KP];
  const int n0  = blockIdx.x * 64;
  const int tid = threadIdx.x;

  if constexpr (A_FP32) {
    const float* A = (const float*)Av;
    for (int c = tid; c < 64 * (K / 8); c += 256) {
      const int row = c / (K / 8), kp = (c % (K / 8)) * 8;
      bf16x8 v = {};
      if (n0 + row < NN) {
        const float* p = A + (size_t)(n0 + row) * K + kp;
        const float4 f0 = *(const float4*)p;
        const float4 f1 = *(const float4*)(p + 4);
        v[0] = f2bf(f0.x); v[1] = f2bf(f0.y); v[2] = f2bf(f0.z); v[3] = f2bf(f0.w);
        v[4] = f2bf(f1.x); v[5] = f2bf(f1.y); v[6] = f2bf(f1.z); v[7] = f2bf(f1.w);
      }
      *(bf16x8*)(As + row * KP + kp) = v;
    }
  } else {
    const unsigned short* A = (const unsigned short*)Av;
    for (int c = tid; c < 64 * (K / 8); c += 256) {
      const int row = c / (K / 8), kp = (c % (K / 8)) * 8;
      bf16x8 v = {};
      if (n0 + row < NN) v = *(const bf16x8*)(A + (size_t)(n0 + row) * K + kp);
      *(bf16x8*)(As + row * KP + kp) = v;
    }
  }

  const int wave = tid >> 6, lane = tid & 63;
  const int i16 = lane & 15, quad = lane >> 4;
  const int r0 = wave * 16 + i16;

  for (int g = 0; g <= NR; ++g) {
    __syncthreads();   // previous group's compute done before Bs overwrite
    const unsigned short* Wg = Wt + (size_t)g * 64 * K;
    for (int c = tid; c < 64 * (K / 8); c += 256) {
      const int row = c / (K / 8), kp = (c % (K / 8)) * 8;
      *(bf16x8*)(Bs + row * KP + kp) = *(const bf16x8*)(Wg + row * K + kp);
    }
    __syncthreads();

    f32x4 acc[4] = {};
#pragma unroll
    for (int kc = 0; kc < K / 32; ++kc) {
      const int k0 = kc * 32 + quad * 8;
      const bf16x8 a0 = *(const bf16x8*)(As + r0 * KP + k0);
      const bf16x8 b0 = *(const bf16x8*)(Bs + (i16)      * KP + k0);
      const bf16x8 b1 = *(const bf16x8*)(Bs + (i16 + 16) * KP + k0);
      const bf16x8 b2 = *(const bf16x8*)(Bs + (i16 + 32) * KP + k0);
      const bf16x8 b3 = *(const bf16x8*)(Bs + (i16 + 48) * KP + k0);
      acc[0] = __builtin_amdgcn_mfma_f32_16x16x32_bf16(a0, b0, acc[0], 0, 0, 0);
      acc[1] = __builtin_amdgcn_mfma_f32_16x16x32_bf16(a0, b1, acc[1], 0, 0, 0);
      acc[2] = __builtin_amdgcn_mfma_f32_16x16x32_bf16(a0, b2, acc[2], 0, 0, 0);
      acc[3] = __builtin_amdgcn_mfma_f32_16x16x32_bf16(a0, b3, acc[3], 0, 0, 0);
    }

    // C/D: row = quad*4 + reg, col = ct*16 + i16
    if (g < NR) {
#pragma unroll
      for (int reg = 0; reg < 4; ++reg) {
        const int n = n0 + wave * 16 + quad * 4 + reg;
        if (n >= NN) continue;
        unsigned short* p = xw + (size_t)n * (NR * 64) + g * 64 + i16;
#pragma unroll
        for (int ct = 0; ct < 4; ++ct) p[ct * 16] = f2bf(acc[ct][reg]);
      }
    } else {
      float bv[4];
#pragma unroll
      for (int ct = 0; ct < 4; ++ct) bv[ct] = bias[ct * 16 + i16];
#pragma unroll
      for (int reg = 0; reg < 4; ++reg) {
        const int n = n0 + wave * 16 + quad * 4 + reg;
        if (n >= NN) continue;
        float* p = root_out + (size_t)n * 64 + i16;
#pragma unroll
        for (int ct = 0; ct < 4; ++ct) p[ct * 16] = acc[ct][reg] + bv[ct];
      }
    }
  }
}

// ---------------- aggregation ----------------
// One wave per dst node. Records prefetched coalesced (lane i -> rec i),
// broadcast by shfl; scale = shfl of register-resident inv[d*8 + r].
template <bool RELU_BF16>
__global__ void __launch_bounds__(256) agg_csr(
    const int* __restrict__ row_start, const int* __restrict__ deg,
    const unsigned* __restrict__ offs, const unsigned short* __restrict__ xw,
    const float* __restrict__ inv, const float* __restrict__ root,
    float* __restrict__ out_f32, unsigned short* __restrict__ out_b16) {
  const int gid  = blockIdx.x * blockDim.x + threadIdx.x;
  const int lane = gid & 63;
  const int d    = gid >> 6;
  if (d >= NN) return;
  const int base = row_start[d];
  const int n    = deg[d];
  const float invv = inv[(d << 3) + (lane & 7)];
  float a0 = 0.f, a1 = 0.f, a2 = 0.f, a3 = 0.f;
  for (int c = 0; c < n; c += 64) {
    const int m = min(64, n - c);
    unsigned off = 0;
    if (lane < m) off = offs[base + c + lane];
    int j = 0;
    for (; j + 4 <= m; j += 4) {
      const unsigned u0 = __shfl(off, j, 64);
      const unsigned u1 = __shfl(off, j + 1, 64);
      const unsigned u2 = __shfl(off, j + 2, 64);
      const unsigned u3 = __shfl(off, j + 3, 64);
      const float s0 = __shfl(invv, (int)((u0 >> 6) & 7), 64);
      const float s1 = __shfl(invv, (int)((u1 >> 6) & 7), 64);
      const float s2 = __shfl(invv, (int)((u2 >> 6) & 7), 64);
      const float s3 = __shfl(invv, (int)((u3 >> 6) & 7), 64);
      a0 += bf2f(xw[u0 + lane]) * s0;
      a1 += bf2f(xw[u1 + lane]) * s1;
      a2 += bf2f(xw[u2 + lane]) * s2;
      a3 += bf2f(xw[u3 + lane]) * s3;
    }
    for (; j < m; ++j) {
      const unsigned u0 = __shfl(off, j, 64);
      const float s0 = __shfl(invv, (int)((u0 >> 6) & 7), 64);
      a0 += bf2f(xw[u0 + lane]) * s0;
    }
  }
  const float v = root[(size_t)d * 64 + lane] + ((a0 + a1) + (a2 + a3));
  if (RELU_BF16) out_b16[(size_t)d * 64 + lane] = f2bf(fmaxf(v, 0.f));
  else           out_f32[(size_t)d * 64 + lane] = v;
}

extern "C" void kernel_launch(void* const* d_in, const int* in_sizes, int n_in,
                              void* d_out, int out_size, void* d_ws, size_t ws_size,
                              hipStream_t stream) {
  const float* x   = (const float*)d_in[0];
  const int*   ei  = (const int*)d_in[1];
  const int*   et  = (const int*)d_in[2];
  const float* W1r = (const float*)d_in[3];
  const float* W1o = (const float*)d_in[4];
  const float* b1  = (const float*)d_in[5];
  const float* W2r = (const float*)d_in[6];
  const float* W2o = (const float*)d_in[7];
  const float* b2  = (const float*)d_in[8];
  float* out = (float*)d_out;

  const int* src = ei;
  const int* dst = ei + NE;

  char* ws = (char*)d_ws;
  size_t off = 0;
  auto alloc = [&](size_t bytes) {
    void* p = ws + off; off += (bytes + 255) & ~(size_t)255; return p;
  };
  int*   cnt       = (int*)alloc((size_t)NN * NR * 4);
  float* inv       = (float*)alloc((size_t)NN * NR * 4);
  int*   row_start = (int*)alloc((size_t)NN * 4);
  int*   deg       = (int*)alloc((size_t)NN * 4);
  int*   cur       = (int*)alloc((size_t)NN * 4);
  int*   cursor    = (int*)alloc(256);
  unsigned* offs   = (unsigned*)alloc((size_t)NE * 4);                     //  6.4 MB
  unsigned short* xw    = (unsigned short*)alloc((size_t)NN * NR * 64 * 2); // 51.2 MB
  unsigned short* hb    = (unsigned short*)alloc((size_t)NN * FH * 2);      //  6.4 MB
  float*          hroot = (float*)alloc((size_t)NN * 64 * 4);               // 12.8 MB
  unsigned short* Wt1   = (unsigned short*)alloc((size_t)(NR + 1) * 64 * FIN * 2);
  unsigned short* Wt2   = (unsigned short*)alloc((size_t)(NR + 1) * 64 * FH * 2);

  hipMemsetAsync(cnt, 0, (size_t)NN * NR * 4, stream);
  hipMemsetAsync(cursor, 0, 256, stream);

  count_kernel<<<(NE + 255) / 256, 256, 0, stream>>>(dst, et, cnt);
  node_setup<<<(NN + 255) / 256, 256, 0, stream>>>(cnt, inv, row_start, deg, cur, cursor);
  scatter_kernel<<<(NE + 255) / 256, 256, 0, stream>>>(src, dst, et, cur, offs);

  cvt_w<FIN><<<((NR + 1) * 64 * FIN + 255) / 256, 256, 0, stream>>>(W1r, W1o, Wt1);
  cvt_w<FH><<<((NR + 1) * 64 * FH + 255) / 256, 256, 0, stream>>>(W2r, W2o, Wt2);

  const int gemm_blocks = (NN + 63) / 64;
  const int agg_blocks  = (NN * 64 + 255) / 256;
  // Layer 1
  gemm_mfma<FIN, true><<<gemm_blocks, 256, 0, stream>>>(x, Wt1, b1, xw, hroot);
  agg_csr<true><<<agg_blocks, 256, 0, stream>>>(row_start, deg, offs, xw, inv, hroot, nullptr, hb);
  // Layer 2
  gemm_mfma<FH, false><<<gemm_blocks, 256, 0, stream>>>(hb, Wt2, b2, xw, out);
  agg_csr<false><<<agg_blocks, 256, 0, stream>>>(row_start, deg, offs, xw, inv, out, out, nullptr);
}